// Round 1
// baseline (1214.453 us; speedup 1.0000x reference)
//
#include <hip/hip_runtime.h>
#include <hip/hip_bf16.h>

#define Bv 256
#define Lv 1024
#define Vv 96
#define Ev 64
#define Hv 256
#define ROWS 16
#define HOFF (Bv * Lv * Vv)   // 25165824
#define EPAD 72               // emb row pad (bf16 elems) to break bank aliasing

typedef __attribute__((ext_vector_type(8))) short bf16x8;
typedef __attribute__((ext_vector_type(4))) float f32x4;

__device__ __forceinline__ unsigned short f2b(float f) {
  unsigned u = __builtin_bit_cast(unsigned, f);
  return (unsigned short)((u + 0x7fffu + ((u >> 16) & 1u)) >> 16);  // RNE fp32->bf16
}

__device__ __forceinline__ float fast_tanh(float x) {
  // tanh(x) = 1 - 2/(exp(2x)+1); exp via v_exp_f32, rcp via v_rcp_f32.
  float e = __builtin_amdgcn_exp2f(x * 2.885390081777927f); // exp(2x)
  return 1.0f - 2.0f * __builtin_amdgcn_rcpf(e + 1.0f);
}

// x may arrive as int32 or int64 (reference dtype is int64). Values are in
// [0,96); for int64 little-endian the odd int32 words are all zero.
__global__ void detect_i64(const int* __restrict__ x, int* __restrict__ flag) {
  if (threadIdx.x == 0 && blockIdx.x == 0) {
    int ok = 1;
    for (int i = 0; i < 64; ++i) ok &= (x[2 * i + 1] == 0);
    *flag = ok;
  }
}

// One workgroup = 16 batch rows, 4 waves; wave w owns hidden cols [64w,64w+64)
// of Wh/Wx and logits cols [32w,32w+32) (wave 3: none). All weights live in
// registers as bf16 MFMA B-fragments; h_t staged in swizzled LDS each step.
__global__ __launch_bounds__(256, 1) void rnn_fused(
    const int* __restrict__ x, const float* __restrict__ h0,
    const float* __restrict__ emb, const float* __restrict__ W_ih,
    const float* __restrict__ b_ih, const float* __restrict__ W_ho,
    const float* __restrict__ b_ho, float* __restrict__ out,
    const int* __restrict__ flagp) {
  const int tid = threadIdx.x;
  const int w   = tid >> 6;   // wave 0..3
  const int ln  = tid & 63;   // lane
  const int lm  = ln & 15;    // MFMA 16-field (A row / B col / D col)
  const int g   = ln >> 4;    // k-group 0..3
  const int r0  = blockIdx.x * ROWS;

  __shared__ __attribute__((aligned(16))) unsigned short s_emb[Vv * EPAD];
  __shared__ __attribute__((aligned(16))) unsigned short s_h[ROWS * Hv];

  // stage embedding table as bf16, padded rows
  for (int idx = tid; idx < Vv * Ev; idx += 256) {
    int row = idx >> 6, col = idx & 63;
    s_emb[row * EPAD + col] = f2b(emb[idx]);
  }
  // stage h_{-1} (input hidden) into swizzled h buffer
  for (int idx = tid; idx < ROWS * Hv; idx += 256) {
    int m = idx >> 8, n = idx & 255;
    s_h[(m << 8) + ((((n >> 3) ^ (m & 7)) << 3) | (n & 7))] =
        f2b(h0[(r0 + m) * Hv + n]);
  }

  // ---- weight fragments (registers, bf16) ----
  bf16x8 wh[4][8];   // Wh: wave cols 64w..64w+63, K=256 (8 frags)
  bf16x8 wx[4][2];   // Wx: same cols, K=64 (2 frags)
  bf16x8 who[2][8];  // W_ho: cols 32w..32w+31 (wave 3 unused)
#pragma unroll
  for (int nt = 0; nt < 4; ++nt) {
    const int n = 64 * w + 16 * nt + lm;
#pragma unroll
    for (int kf = 0; kf < 8; ++kf)
#pragma unroll
      for (int i = 0; i < 8; ++i)
        wh[nt][kf][i] = (short)f2b(W_ih[(Ev + 32 * kf + 8 * g + i) * Hv + n]);
#pragma unroll
    for (int kf = 0; kf < 2; ++kf)
#pragma unroll
      for (int i = 0; i < 8; ++i)
        wx[nt][kf][i] = (short)f2b(W_ih[(32 * kf + 8 * g + i) * Hv + n]);
  }
#pragma unroll
  for (int j = 0; j < 2; ++j) {
    const int n = 32 * w + 16 * j + lm;
#pragma unroll
    for (int kf = 0; kf < 8; ++kf)
#pragma unroll
      for (int i = 0; i < 8; ++i)
        who[j][kf][i] =
            (n < Vv) ? (short)f2b(W_ho[(32 * kf + 8 * g + i) * Vv + n]) : (short)0;
  }
  float bih[4];
#pragma unroll
  for (int nt = 0; nt < 4; ++nt) bih[nt] = b_ih[64 * w + 16 * nt + lm];
  float bho[2];
#pragma unroll
  for (int j = 0; j < 2; ++j) {
    int n = 32 * w + 16 * j + lm;
    bho[j] = (n < Vv) ? b_ho[n] : 0.0f;
  }

  const int flag = *flagp;                 // 1 => x is int64
  const int xoff = (r0 + lm) * Lv;
  const int* xp = x + (flag ? 2 * xoff : xoff);
  const int xstride = flag ? 2 : 1;

  __syncthreads();

  for (int t = 0; t < Lv; ++t) {
    // A-fragments of h_{t-1} (swizzled b128 reads)
    bf16x8 af[8];
#pragma unroll
    for (int kf = 0; kf < 8; ++kf)
      af[kf] = *(const bf16x8*)&s_h[(lm << 8) + (((4 * kf + g) ^ (lm & 7)) << 3)];

    // logits for step t-1 (skewed by one iteration)
    if (t > 0 && w < 3) {
      f32x4 l0 = {bho[0], bho[0], bho[0], bho[0]};
      f32x4 l1 = {bho[1], bho[1], bho[1], bho[1]};
#pragma unroll
      for (int kf = 0; kf < 8; ++kf) {
        l0 = __builtin_amdgcn_mfma_f32_16x16x32_bf16(af[kf], who[0][kf], l0, 0, 0, 0);
        l1 = __builtin_amdgcn_mfma_f32_16x16x32_bf16(af[kf], who[1][kf], l1, 0, 0, 0);
      }
      const int n0 = 32 * w + lm;
#pragma unroll
      for (int rr = 0; rr < 4; ++rr) {
        int o = ((r0 + 4 * g + rr) * Lv + (t - 1)) * Vv;
        out[o + n0] = l0[rr];
        out[o + n0 + 16] = l1[rr];
      }
    }

    // embedding A-fragments for step t
    const int xi = xp[t * xstride];
    const unsigned short* ep = &s_emb[xi * EPAD + 8 * g];
    bf16x8 ef0 = *(const bf16x8*)ep;
    bf16x8 ef1 = *(const bf16x8*)(ep + 32);

    // preact = b_ih + emb@Wx + h_{t-1}@Wh
    f32x4 acc[4];
#pragma unroll
    for (int nt = 0; nt < 4; ++nt) {
      f32x4 a = {bih[nt], bih[nt], bih[nt], bih[nt]};
      a = __builtin_amdgcn_mfma_f32_16x16x32_bf16(ef0, wx[nt][0], a, 0, 0, 0);
      a = __builtin_amdgcn_mfma_f32_16x16x32_bf16(ef1, wx[nt][1], a, 0, 0, 0);
#pragma unroll
      for (int kf = 0; kf < 8; ++kf)
        a = __builtin_amdgcn_mfma_f32_16x16x32_bf16(af[kf], wh[nt][kf], a, 0, 0, 0);
      acc[nt] = a;
    }

    __syncthreads();  // all waves done reading s_h
#pragma unroll
    for (int nt = 0; nt < 4; ++nt) {
#pragma unroll
      for (int rr = 0; rr < 4; ++rr) {
        float hv = fast_tanh(acc[nt][rr]);
        acc[nt][rr] = hv;
        const int m = 4 * g + rr, n = 64 * w + 16 * nt + lm;  // C/D: col=lm, row=4g+rr
        s_h[(m << 8) + ((((n >> 3) ^ (m & 7)) << 3) | (n & 7))] = f2b(hv);
      }
    }
    __syncthreads();  // h_t visible

    if (t == Lv - 1) {  // final hidden, exact fp32 from C/D registers
#pragma unroll
      for (int nt = 0; nt < 4; ++nt)
#pragma unroll
        for (int rr = 0; rr < 4; ++rr)
          out[HOFF + (r0 + 4 * g + rr) * Hv + 64 * w + 16 * nt + lm] = acc[nt][rr];
    }
  }

  // epilogue: logits for t = L-1
  if (w < 3) {
    bf16x8 af[8];
#pragma unroll
    for (int kf = 0; kf < 8; ++kf)
      af[kf] = *(const bf16x8*)&s_h[(lm << 8) + (((4 * kf + g) ^ (lm & 7)) << 3)];
    f32x4 l0 = {bho[0], bho[0], bho[0], bho[0]};
    f32x4 l1 = {bho[1], bho[1], bho[1], bho[1]};
#pragma unroll
    for (int kf = 0; kf < 8; ++kf) {
      l0 = __builtin_amdgcn_mfma_f32_16x16x32_bf16(af[kf], who[0][kf], l0, 0, 0, 0);
      l1 = __builtin_amdgcn_mfma_f32_16x16x32_bf16(af[kf], who[1][kf], l1, 0, 0, 0);
    }
    const int n0 = 32 * w + lm;
#pragma unroll
    for (int rr = 0; rr < 4; ++rr) {
      int o = ((r0 + 4 * g + rr) * Lv + (Lv - 1)) * Vv;
      out[o + n0] = l0[rr];
      out[o + n0 + 16] = l1[rr];
    }
  }
}

extern "C" void kernel_launch(void* const* d_in, const int* in_sizes, int n_in,
                              void* d_out, int out_size, void* d_ws, size_t ws_size,
                              hipStream_t stream) {
  const int* x     = (const int*)d_in[0];
  const float* h0  = (const float*)d_in[1];
  const float* emb = (const float*)d_in[2];
  const float* Wih = (const float*)d_in[3];
  const float* bih = (const float*)d_in[4];
  const float* Who = (const float*)d_in[5];
  const float* bho = (const float*)d_in[6];
  float* out = (float*)d_out;
  int* flag = (int*)d_ws;

  detect_i64<<<1, 64, 0, stream>>>(x, flag);
  rnn_fused<<<16, 256, 0, stream>>>(x, h0, emb, Wih, bih, Who, bho, out, flag);
}

// Round 2
// 751.045 us; speedup vs baseline: 1.6170x; 1.6170x over previous
//
#include <hip/hip_runtime.h>
#include <hip/hip_bf16.h>

#define Lv 1024
#define Vv 96
#define Ev 64
#define Hv 256
#define ROWS 16
#define HOFF (256 * 1024 * 96)
#define EPAD 72
#define HBUF (ROWS * Hv)  // 4096 ushorts per h buffer

typedef __attribute__((ext_vector_type(8))) short bf16x8;
typedef __attribute__((ext_vector_type(4))) float f32x4;

__device__ __forceinline__ unsigned short f2b(float f) {
  unsigned u = __builtin_bit_cast(unsigned, f);
  return (unsigned short)((u + 0x7fffu + ((u >> 16) & 1u)) >> 16);  // RNE
}
__device__ __forceinline__ unsigned cvtpk_bf16(float lo, float hi) {
  unsigned r;
  asm("v_cvt_pk_bf16_f32 %0, %1, %2" : "=v"(r) : "v"(lo), "v"(hi));
  return r;
}
__device__ __forceinline__ float fast_tanh(float x) {
  float e = __builtin_amdgcn_exp2f(x * 2.885390081777927f);  // exp(2x)
  return 1.0f - 2.0f * __builtin_amdgcn_rcpf(e + 1.0f);
}
// One barrier per step: manual lgkmcnt(0) (LDS ordering) but NO vmcnt drain,
// so logits global stores retire asynchronously across steps.
__device__ __forceinline__ void step_barrier() {
  asm volatile("s_waitcnt lgkmcnt(0)\n\ts_barrier" ::: "memory");
  __builtin_amdgcn_sched_barrier(0);
}

__global__ void detect_i64(const int* __restrict__ x, int* __restrict__ flag) {
  if (threadIdx.x == 0 && blockIdx.x == 0) {
    int ok = 1;
    for (int i = 0; i < 64; ++i) ok &= (x[2 * i + 1] == 0);
    *flag = ok;
  }
}

// 16 WGs x 16 batch rows, 8 waves each. Wave w: hidden cols [32w,32w+32),
// logits cols [16w,16w+16) for w<6. Weights register-resident (bf16 B-frags).
// s_h double-buffered; x staged in LDS (u8); emb frags prefetched 1 step ahead.
__global__ __launch_bounds__(512, 2) void rnn_fused(
    const int* __restrict__ x, const float* __restrict__ h0,
    const float* __restrict__ emb, const float* __restrict__ W_ih,
    const float* __restrict__ b_ih, const float* __restrict__ W_ho,
    const float* __restrict__ b_ho, float* __restrict__ out,
    const int* __restrict__ flagp) {
  const int tid = threadIdx.x;
  const int w = tid >> 6, ln = tid & 63, lm = ln & 15, g = ln >> 4;
  const int r0 = blockIdx.x * ROWS;

  __shared__ __attribute__((aligned(16))) unsigned short s_emb[Vv * EPAD];
  __shared__ __attribute__((aligned(16))) unsigned short s_h[2 * HBUF];
  __shared__ unsigned char s_x[Lv * ROWS];

  const int flag = *flagp;  // 1 => x is int64

  for (int idx = tid; idx < Vv * Ev; idx += 512)
    s_emb[(idx >> 6) * EPAD + (idx & 63)] = f2b(emb[idx]);
  for (int idx = tid; idx < ROWS * Hv; idx += 512) {  // h_{-1} -> buf1
    int m = idx >> 8, n = idx & 255;
    s_h[HBUF + (m << 8) + ((((n >> 3) ^ (m & 7)) << 3) | (n & 7))] =
        f2b(h0[(r0 + m) * Hv + n]);
  }
  for (int idx = tid; idx < ROWS * Lv; idx += 512) {  // x, transposed u8
    int row = idx >> 10, t = idx & 1023;
    int src = (r0 + row) * Lv + t;
    int v = flag ? x[2 * src] : x[src];
    s_x[t * ROWS + row] = (unsigned char)v;
  }

  // ---- register-resident weights ----
  bf16x8 wh[2][8], wx[2][2], who[8];
  float bih[2], bhov = 0.0f;
#pragma unroll
  for (int nt = 0; nt < 2; ++nt) {
    const int n = 32 * w + 16 * nt + lm;
    bih[nt] = b_ih[n];
#pragma unroll
    for (int kf = 0; kf < 8; ++kf)
#pragma unroll
      for (int i = 0; i < 8; ++i)
        wh[nt][kf][i] = (short)f2b(W_ih[(Ev + 32 * kf + 8 * g + i) * Hv + n]);
#pragma unroll
    for (int kf = 0; kf < 2; ++kf)
#pragma unroll
      for (int i = 0; i < 8; ++i)
        wx[nt][kf][i] = (short)f2b(W_ih[(32 * kf + 8 * g + i) * Hv + n]);
  }
  if (w < 6) {
    const int n = 16 * w + lm;
    bhov = b_ho[n];
#pragma unroll
    for (int kf = 0; kf < 8; ++kf)
#pragma unroll
      for (int i = 0; i < 8; ++i)
        who[kf][i] = (short)f2b(W_ho[(32 * kf + 8 * g + i) * Vv + n]);
  }

  // ---- loop-invariant LDS / global addresses ----
  const unsigned short* ra[8];
#pragma unroll
  for (int kf = 0; kf < 8; ++kf)
    ra[kf] = &s_h[(lm << 8) + (((4 * kf + g) ^ (lm & 7)) << 3)];
  unsigned short* wa[8];
#pragma unroll
  for (int nt = 0; nt < 2; ++nt)
#pragma unroll
    for (int rr = 0; rr < 4; ++rr) {
      int m = 4 * g + rr, n = 32 * w + 16 * nt + lm;
      wa[nt * 4 + rr] = &s_h[(m << 8) + ((((n >> 3) ^ (m & 7)) << 3) | (n & 7))];
    }
  float* ob[4] = {out, out, out, out};
  if (w < 6) {
#pragma unroll
    for (int rr = 0; rr < 4; ++rr)
      ob[rr] = out + (size_t)(r0 + 4 * g + rr) * (Lv * Vv) + 16 * w + lm;
  }

  __syncthreads();

  bf16x8 ef0, ef1;
  {
    int xi = s_x[lm];  // t = 0
    const unsigned short* ep = &s_emb[xi * EPAD + 8 * g];
    ef0 = *(const bf16x8*)ep;
    ef1 = *(const bf16x8*)(ep + 32);
  }

#define STEP(TT, RB, WB, DOLOG, LAST)                                              \
  do {                                                                             \
    bf16x8 af[8];                                                                  \
    _Pragma("unroll") for (int kf = 0; kf < 8; ++kf)                               \
        af[kf] = *(const bf16x8*)(ra[kf] + (RB));                                  \
    f32x4 a0 = {bih[0], bih[0], bih[0], bih[0]};                                   \
    f32x4 a1 = {bih[1], bih[1], bih[1], bih[1]};                                   \
    a0 = __builtin_amdgcn_mfma_f32_16x16x32_bf16(ef0, wx[0][0], a0, 0, 0, 0);      \
    a1 = __builtin_amdgcn_mfma_f32_16x16x32_bf16(ef0, wx[1][0], a1, 0, 0, 0);      \
    a0 = __builtin_amdgcn_mfma_f32_16x16x32_bf16(ef1, wx[0][1], a0, 0, 0, 0);      \
    a1 = __builtin_amdgcn_mfma_f32_16x16x32_bf16(ef1, wx[1][1], a1, 0, 0, 0);      \
    _Pragma("unroll") for (int kf = 0; kf < 8; ++kf) {                             \
      a0 = __builtin_amdgcn_mfma_f32_16x16x32_bf16(af[kf], wh[0][kf], a0, 0, 0, 0);\
      a1 = __builtin_amdgcn_mfma_f32_16x16x32_bf16(af[kf], wh[1][kf], a1, 0, 0, 0);\
    }                                                                              \
    if ((DOLOG) && w < 6) {                                                        \
      f32x4 l = {bhov, bhov, bhov, bhov};                                          \
      _Pragma("unroll") for (int kf = 0; kf < 8; ++kf)                             \
          l = __builtin_amdgcn_mfma_f32_16x16x32_bf16(af[kf], who[kf], l, 0, 0, 0);\
      const size_t o = (size_t)((TT)-1) * Vv;                                      \
      ob[0][o] = l[0]; ob[1][o] = l[1]; ob[2][o] = l[2]; ob[3][o] = l[3];          \
    }                                                                              \
    {                                                                              \
      int tn = ((TT) + 1 < Lv) ? (TT) + 1 : (Lv - 1);                              \
      int xi = s_x[tn * ROWS + lm];                                                \
      const unsigned short* ep = &s_emb[xi * EPAD + 8 * g];                        \
      ef0 = *(const bf16x8*)ep;                                                    \
      ef1 = *(const bf16x8*)(ep + 32);                                             \
    }                                                                              \
    float th0 = fast_tanh(a0[0]), th1 = fast_tanh(a0[1]);                          \
    float th2 = fast_tanh(a0[2]), th3 = fast_tanh(a0[3]);                          \
    float th4 = fast_tanh(a1[0]), th5 = fast_tanh(a1[1]);                          \
    float th6 = fast_tanh(a1[2]), th7 = fast_tanh(a1[3]);                          \
    unsigned p01 = cvtpk_bf16(th0, th1), p23 = cvtpk_bf16(th2, th3);               \
    unsigned p45 = cvtpk_bf16(th4, th5), p67 = cvtpk_bf16(th6, th7);               \
    wa[0][WB] = (unsigned short)p01;                                               \
    wa[1][WB] = (unsigned short)(p01 >> 16);                                       \
    wa[2][WB] = (unsigned short)p23;                                               \
    wa[3][WB] = (unsigned short)(p23 >> 16);                                       \
    wa[4][WB] = (unsigned short)p45;                                               \
    wa[5][WB] = (unsigned short)(p45 >> 16);                                       \
    wa[6][WB] = (unsigned short)p67;                                               \
    wa[7][WB] = (unsigned short)(p67 >> 16);                                       \
    if (LAST) {                                                                    \
      float* fh = out + HOFF + (size_t)(r0 + 4 * g) * Hv + 32 * w + lm;            \
      fh[0 * Hv] = th0; fh[1 * Hv] = th1; fh[2 * Hv] = th2; fh[3 * Hv] = th3;      \
      fh[0 * Hv + 16] = th4; fh[1 * Hv + 16] = th5;                                \
      fh[2 * Hv + 16] = th6; fh[3 * Hv + 16] = th7;                                \
    }                                                                              \
    step_barrier();                                                                \
  } while (0)

  STEP(0, HBUF, 0, 0, 0);  // h_{-1} in buf1 -> h_0 in buf0, no logits yet
  for (int t = 1; t < Lv - 1; t += 2) {
    STEP(t, 0, HBUF, 1, 0);
    STEP(t + 1, HBUF, 0, 1, 0);
  }
  STEP(Lv - 1, 0, HBUF, 1, 1);  // also stores final hidden (fp32, pre-round)

  // epilogue: logits for t = Lv-1 (h_{Lv-1} is in buf1)
  if (w < 6) {
    bf16x8 af[8];
#pragma unroll
    for (int kf = 0; kf < 8; ++kf) af[kf] = *(const bf16x8*)(ra[kf] + HBUF);
    f32x4 l = {bhov, bhov, bhov, bhov};
#pragma unroll
    for (int kf = 0; kf < 8; ++kf)
      l = __builtin_amdgcn_mfma_f32_16x16x32_bf16(af[kf], who[kf], l, 0, 0, 0);
    const size_t o = (size_t)(Lv - 1) * Vv;
    ob[0][o] = l[0]; ob[1][o] = l[1]; ob[2][o] = l[2]; ob[3][o] = l[3];
  }
#undef STEP
}

extern "C" void kernel_launch(void* const* d_in, const int* in_sizes, int n_in,
                              void* d_out, int out_size, void* d_ws, size_t ws_size,
                              hipStream_t stream) {
  const int* x     = (const int*)d_in[0];
  const float* h0  = (const float*)d_in[1];
  const float* emb = (const float*)d_in[2];
  const float* Wih = (const float*)d_in[3];
  const float* bih = (const float*)d_in[4];
  const float* Who = (const float*)d_in[5];
  const float* bho = (const float*)d_in[6];
  float* out = (float*)d_out;
  int* flag = (int*)d_ws;

  detect_i64<<<1, 64, 0, stream>>>(x, flag);
  rnn_fused<<<16, 512, 0, stream>>>(x, h0, emb, Wih, bih, Who, bho, out, flag);
}